// Round 2
// baseline (386.413 us; speedup 1.0000x reference)
//
#include <hip/hip_runtime.h>
#include <hip/hip_cooperative_groups.h>

namespace cg = cooperative_groups;

#define LN_EPS 1e-5f
constexpr int B_ = 8;
constexpr int N_ = 10000;
constexpr int C_ = 256;                       // 64 float4 per row
constexpr int NSLICES = 64;                   // slices per batch
constexpr int RPS = (N_ + NSLICES - 1) / NSLICES;  // 157 rows/slice
constexpr int GRID = B_ * NSLICES;            // 512 blocks = 2/CU

// ws layout: partials[NSLICES*B_*C_] then agg[B_*C_]
__global__ __launch_bounds__(256, 2) void fused_gcn_ln_kernel(
    const float* __restrict__ x, const float* __restrict__ W,
    const float* __restrict__ bias, const float* __restrict__ gamma,
    const float* __restrict__ beta, float* __restrict__ out,
    float* __restrict__ ws)
{
    float* partials = ws;
    float* agg      = ws + (size_t)NSLICES * B_ * C_;

    const int t    = threadIdx.x;
    const int wave = t >> 6;     // 0..3
    const int lane = t & 63;     // float4 column
    const int b    = blockIdx.x >> 6;          // /NSLICES
    const int s    = blockIdx.x & (NSLICES - 1);

    const int nStart = s * RPS;
    const int nEnd   = min(N_, nStart + RPS);

    const float4* xb = reinterpret_cast<const float4*>(x) + (size_t)b * N_ * 64;

    // ---------- Phase 1: partial column sums for this (b, slice) ----------
    float4 acc = make_float4(0.f, 0.f, 0.f, 0.f);
    for (int n = nStart + wave; n < nEnd; n += 4) {
        float4 v = xb[(size_t)n * 64 + lane];
        acc.x += v.x; acc.y += v.y; acc.z += v.z; acc.w += v.w;
    }

    __shared__ float4 red[256];
    __shared__ float  mean[C_];
    red[t] = acc;
    __syncthreads();
    if (t < 64) {
        float4 a0 = red[t], a1 = red[t + 64], a2 = red[t + 128], a3 = red[t + 192];
        float4 sum;
        sum.x = a0.x + a1.x + a2.x + a3.x;
        sum.y = a0.y + a1.y + a2.y + a3.y;
        sum.z = a0.z + a1.z + a2.z + a3.z;
        sum.w = a0.w + a1.w + a2.w + a3.w;
        reinterpret_cast<float4*>(partials)[(size_t)(s * B_ + b) * 64 + t] = sum;
    }
    __threadfence();          // device-scope release of partials
    cg::this_grid().sync();
    __threadfence();          // device-scope acquire

    // ---------- Phase 2: blocks 0..7 reduce partials -> mean, GEMV -> agg ----------
    if (blockIdx.x < B_) {
        const int bb = blockIdx.x;
        float sum = 0.f;
        for (int ss = 0; ss < NSLICES; ++ss)
            sum += partials[(size_t)(ss * B_ + bb) * C_ + t];
        mean[t] = sum * (1.0f / (float)N_);
        __syncthreads();

        const float4* wrow = reinterpret_cast<const float4*>(W) + (size_t)t * 64;
        const float4* m4   = reinterpret_cast<const float4*>(mean);
        float a = bias[t];
#pragma unroll 8
        for (int i = 0; i < 64; ++i) {
            float4 w = wrow[i], m = m4[i];
            a += w.x * m.x + w.y * m.y + w.z * m.z + w.w * m.w;
        }
        agg[bb * C_ + t] = a;
        __threadfence();      // release agg
    }
    cg::this_grid().sync();
    __threadfence();          // acquire agg

    // ---------- Phase 3: residual + LayerNorm on the SAME rows (L2/L3 locality) ----------
    float4 ag = reinterpret_cast<const float4*>(agg)[(size_t)b * 64 + lane];
    float4 g  = reinterpret_cast<const float4*>(gamma)[lane];
    float4 be = reinterpret_cast<const float4*>(beta)[lane];
    float4* outb = reinterpret_cast<float4*>(out) + (size_t)b * N_ * 64;

    for (int n = nStart + wave; n < nEnd; n += 4) {
        float4 v = xb[(size_t)n * 64 + lane];
        v.x += ag.x; v.y += ag.y; v.z += ag.z; v.w += ag.w;

        float sm = v.x + v.y + v.z + v.w;
        float sq = v.x * v.x + v.y * v.y + v.z * v.z + v.w * v.w;
#pragma unroll
        for (int m = 32; m >= 1; m >>= 1) {
            sm += __shfl_xor(sm, m, 64);
            sq += __shfl_xor(sq, m, 64);
        }
        const float mu  = sm * (1.0f / (float)C_);
        const float var = sq * (1.0f / (float)C_) - mu * mu;
        const float rs  = rsqrtf(var + LN_EPS);

        float4 o;
        o.x = (v.x - mu) * rs * g.x + be.x;
        o.y = (v.y - mu) * rs * g.y + be.y;
        o.z = (v.z - mu) * rs * g.z + be.z;
        o.w = (v.w - mu) * rs * g.w + be.w;
        outb[(size_t)n * 64 + lane] = o;
    }
}

extern "C" void kernel_launch(void* const* d_in, const int* in_sizes, int n_in,
                              void* d_out, int out_size, void* d_ws, size_t ws_size,
                              hipStream_t stream) {
    const float* x     = (const float*)d_in[0];   // [B,N,C]
    const float* W     = (const float*)d_in[1];   // [C,C] (out,in)
    const float* bias  = (const float*)d_in[2];   // [C]
    const float* gamma = (const float*)d_in[3];   // [C]
    const float* beta  = (const float*)d_in[4];   // [C]
    float* out = (float*)d_out;
    float* ws  = (float*)d_ws;   // needs (NSLICES*B_*C_ + B_*C_)*4 = ~532 KB

    void* args[] = {(void*)&x, (void*)&W, (void*)&bias, (void*)&gamma,
                    (void*)&beta, (void*)&out, (void*)&ws};
    hipLaunchCooperativeKernel(reinterpret_cast<const void*>(fused_gcn_ln_kernel),
                               dim3(GRID), dim3(256), args, 0, stream);
}

// Round 3
// 180.175 us; speedup vs baseline: 2.1447x; 2.1447x over previous
//
#include <hip/hip_runtime.h>

#define LN_EPS 1e-5f
constexpr int B_ = 8;
constexpr int N_ = 10000;
constexpr int C_ = 256;                 // 64 float4 per row
constexpr int NSLICES = 128;            // slices per batch
constexpr int RPS = 79;                 // ceil(10000/128); 128*79 = 10112 >= 10000
constexpr int GRID1 = B_ * NSLICES;     // 1024 blocks = 4/CU, 16 waves/CU

// ---------------- Kernel 1: partial column sums over N ----------------
// block = 256 = 4 waves; wave w sums rows {nStart+w, +4, +8, ...}, unroll x2.
__global__ __launch_bounds__(256) void colsum_kernel(
    const float* __restrict__ x, float* __restrict__ partials)
{
    const int t    = threadIdx.x;
    const int wave = t >> 6;
    const int lane = t & 63;
    const int b    = blockIdx.x >> 7;          // / NSLICES
    const int s    = blockIdx.x & (NSLICES - 1);

    const int nStart = s * RPS;
    const int nEnd   = min(N_, nStart + RPS);

    const float4* xb = reinterpret_cast<const float4*>(x) + (size_t)b * N_ * 64;

    float4 a0 = make_float4(0.f, 0.f, 0.f, 0.f);
    float4 a1 = make_float4(0.f, 0.f, 0.f, 0.f);
    int n = nStart + wave;
    for (; n + 4 < nEnd; n += 8) {
        float4 v0 = xb[(size_t)n * 64 + lane];
        float4 v1 = xb[(size_t)(n + 4) * 64 + lane];
        a0.x += v0.x; a0.y += v0.y; a0.z += v0.z; a0.w += v0.w;
        a1.x += v1.x; a1.y += v1.y; a1.z += v1.z; a1.w += v1.w;
    }
    if (n < nEnd) {
        float4 v0 = xb[(size_t)n * 64 + lane];
        a0.x += v0.x; a0.y += v0.y; a0.z += v0.z; a0.w += v0.w;
    }
    a0.x += a1.x; a0.y += a1.y; a0.z += a1.z; a0.w += a1.w;

    __shared__ float4 red[256];
    red[t] = a0;
    __syncthreads();
    if (t < 64) {
        float4 r0 = red[t], r1 = red[t + 64], r2 = red[t + 128], r3 = red[t + 192];
        float4 sum;
        sum.x = r0.x + r1.x + r2.x + r3.x;
        sum.y = r0.y + r1.y + r2.y + r3.y;
        sum.z = r0.z + r1.z + r2.z + r3.z;
        sum.w = r0.w + r1.w + r2.w + r3.w;
        reinterpret_cast<float4*>(partials)[(size_t)(s * B_ + b) * 64 + t] = sum;
    }
}

// ---------------- Kernel 2: reduce partials -> mean, tiny GEMV -> agg ----------------
__global__ __launch_bounds__(256) void agg_kernel(
    const float* __restrict__ partials, const float* __restrict__ W,
    const float* __restrict__ bias, float* __restrict__ agg)
{
    const int b = blockIdx.x;
    const int t = threadIdx.x;

    float sum = 0.f;
#pragma unroll 4
    for (int s = 0; s < NSLICES; ++s)
        sum += partials[(size_t)(s * B_ + b) * C_ + t];

    __shared__ float mean[C_];
    mean[t] = sum * (1.0f / (float)N_);
    __syncthreads();

    const float4* wrow = reinterpret_cast<const float4*>(W) + (size_t)t * 64;
    const float4* m4   = reinterpret_cast<const float4*>(mean);
    float a = bias[t];
#pragma unroll 8
    for (int i = 0; i < 64; ++i) {
        float4 w = wrow[i], m = m4[i];
        a += w.x * m.x + w.y * m.y + w.z * m.z + w.w * m.w;
    }
    agg[b * C_ + t] = a;
}

// ---------------- Kernel 3: residual + LayerNorm ----------------
// 8 rows/block: wave w handles rows blk*8 + 2w and +2w+1, fully unrolled
// (two independent load->reduce->store chains per wave).
__global__ __launch_bounds__(256) void ln_kernel(
    const float* __restrict__ x, const float* __restrict__ agg,
    const float* __restrict__ gamma, const float* __restrict__ beta,
    float* __restrict__ out)
{
    const int t    = threadIdx.x;
    const int wave = t >> 6;
    const int lane = t & 63;
    const size_t row0 = (size_t)blockIdx.x * 8 + wave * 2;   // row0 even; 10000 is even
    const int b = (row0 >= (size_t)N_) ? 1 : 0;              // blocks never span b

    const float4* xr = reinterpret_cast<const float4*>(x) + row0 * 64;
    float4*      orr = reinterpret_cast<float4*>(out) + row0 * 64;

    float4 ag = reinterpret_cast<const float4*>(agg)[(size_t)b * 64 + lane];
    float4 g  = reinterpret_cast<const float4*>(gamma)[lane];
    float4 be = reinterpret_cast<const float4*>(beta)[lane];

    float4 v0 = xr[lane];
    float4 v1 = xr[64 + lane];

    v0.x += ag.x; v0.y += ag.y; v0.z += ag.z; v0.w += ag.w;
    v1.x += ag.x; v1.y += ag.y; v1.z += ag.z; v1.w += ag.w;

    float s0  = v0.x + v0.y + v0.z + v0.w;
    float q0  = v0.x * v0.x + v0.y * v0.y + v0.z * v0.z + v0.w * v0.w;
    float s1  = v1.x + v1.y + v1.z + v1.w;
    float q1  = v1.x * v1.x + v1.y * v1.y + v1.z * v1.z + v1.w * v1.w;
#pragma unroll
    for (int m = 32; m >= 1; m >>= 1) {
        s0 += __shfl_xor(s0, m, 64);
        q0 += __shfl_xor(q0, m, 64);
        s1 += __shfl_xor(s1, m, 64);
        q1 += __shfl_xor(q1, m, 64);
    }

    const float mu0 = s0 * (1.0f / (float)C_);
    const float rs0 = rsqrtf(q0 * (1.0f / (float)C_) - mu0 * mu0 + LN_EPS);
    const float mu1 = s1 * (1.0f / (float)C_);
    const float rs1 = rsqrtf(q1 * (1.0f / (float)C_) - mu1 * mu1 + LN_EPS);

    float4 o0, o1;
    o0.x = (v0.x - mu0) * rs0 * g.x + be.x;
    o0.y = (v0.y - mu0) * rs0 * g.y + be.y;
    o0.z = (v0.z - mu0) * rs0 * g.z + be.z;
    o0.w = (v0.w - mu0) * rs0 * g.w + be.w;
    o1.x = (v1.x - mu1) * rs1 * g.x + be.x;
    o1.y = (v1.y - mu1) * rs1 * g.y + be.y;
    o1.z = (v1.z - mu1) * rs1 * g.z + be.z;
    o1.w = (v1.w - mu1) * rs1 * g.w + be.w;

    orr[lane]      = o0;
    orr[64 + lane] = o1;
}

extern "C" void kernel_launch(void* const* d_in, const int* in_sizes, int n_in,
                              void* d_out, int out_size, void* d_ws, size_t ws_size,
                              hipStream_t stream) {
    const float* x     = (const float*)d_in[0];   // [B,N,C]
    const float* W     = (const float*)d_in[1];   // [C,C] (out,in)
    const float* bias  = (const float*)d_in[2];   // [C]
    const float* gamma = (const float*)d_in[3];   // [C]
    const float* beta  = (const float*)d_in[4];   // [C]
    float* out = (float*)d_out;

    // ws: [partials: NSLICES*B*C floats = 1 MB][agg: B*C floats]
    float* partials = (float*)d_ws;
    float* agg      = partials + (size_t)NSLICES * B_ * C_;

    colsum_kernel<<<GRID1, 256, 0, stream>>>(x, partials);
    agg_kernel<<<B_, 256, 0, stream>>>(partials, W, bias, agg);
    ln_kernel<<<(B_ * N_) / 8, 256, 0, stream>>>(x, agg, gamma, beta, out);
}